// Round 1
// baseline (359.392 us; speedup 1.0000x reference)
//
#include <hip/hip_runtime.h>
#include <hip/hip_fp16.h>

typedef _Float16 f16x8 __attribute__((ext_vector_type(8)));
typedef float f32x4 __attribute__((ext_vector_type(4)));

#define T 64          // points per block
#define S 328         // LDS row stride in fp16: Kpad_max(320)+8; 328%64==8 -> 2-way (free) banks

struct LayerPtrs {
  const float* w[8];
  const float* b[8];
};

// Weight fragment storage (in d_ws), per layer: [kc][ntg 0..15][lane 0..63][j 0..7] fp16
// element j of (kc,ntg,lane) = W[kc*32 + (lane>>4)*8 + j][ntg*16 + (lane&15)]  (0 if padded)
// Layer 4 row map inserts a zero row at r==39 (LDS col 39 is a permanent zero gap):
//   r<39 -> w4 row r (emb part), r==39 -> 0, 40<=r<296 -> w4 row r-1 (x part), r>=296 -> 0.

__global__ void prep_weights(LayerPtrs P, f16x8* __restrict__ wf) {
  int gid = blockIdx.x * 256 + threadIdx.x;   // one 8-elem fragment group per thread
  if (gid >= 61440) return;
  const int WOFF8[9] = {0,2048,10240,18432,26624,36864,45056,53248,61440};
  const int DIN[8]   = {39,256,256,256,295,256,256,256};
  int l = 0;
  while (gid >= WOFF8[l+1]) ++l;
  int f    = gid - WOFF8[l];
  int lane = f & 63;
  int t2   = f >> 6;
  int ntg  = t2 & 15;
  int kc   = t2 >> 4;
  int col  = (ntg << 4) + (lane & 15);
  int rbase = kc * 32 + ((lane >> 4) << 3);
  const float* w = P.w[l];
  f16x8 v;
#pragma unroll
  for (int j = 0; j < 8; ++j) {
    int r = rbase + j;
    float x = 0.f;
    if (l == 4) {
      if (r < 39)                 x = w[r * 256 + col];
      else if (r >= 40 && r < 296) x = w[(r - 1) * 256 + col];
    } else {
      if (r < DIN[l])             x = w[r * 256 + col];
    }
    v[j] = (_Float16)x;
  }
  wf[gid] = v;
}

__global__ __launch_bounds__(256, 3)
void mlp_fused(const float* __restrict__ points,
               LayerPtrs P,
               const f16x8* __restrict__ wf,
               const float* __restrict__ wsdf,
               const float* __restrict__ bsdf,
               float* __restrict__ out) {
  __shared__ __align__(16) _Float16 X[T * S];   // 41984 B
  const int tid = threadIdx.x;
  const int blk = blockIdx.x;

  // ---- embedding: cols 0..38 = [sin(18)|cos(18)|xyz(3)]; col 39 zero gap;
  //      cols 39..63 zero (layer-0 K-pad); cols 296..319 zero (layer-4 K-pad) ----
  if (tid < T) {
    int p = blk * T + tid;
    float xyz[3] = {points[p*3+0], points[p*3+1], points[p*3+2]};
    _Float16* row = &X[tid * S];
#pragma unroll
    for (int c = 0; c < 3; ++c) {
      float fr = 1.f;
#pragma unroll
      for (int k = 0; k < 6; ++k) {
        float e = xyz[c] * fr;
        row[c*6 + k]      = (_Float16)sinf(e);
        row[18 + c*6 + k] = (_Float16)cosf(e);
        fr *= 2.f;
      }
      row[36 + c] = (_Float16)xyz[c];
    }
    for (int c = 39; c < 64; ++c)  row[c] = (_Float16)0.f;
    for (int c = 296; c < 320; ++c) row[c] = (_Float16)0.f;
  }
  __syncthreads();

  const int lane = tid & 63;
  const int wv   = tid >> 6;      // wave id -> output col group [64*wv, 64*wv+64)
  const int l16  = lane & 15;
  const int quad = lane >> 4;

  const int KP[8]    = {64,256,256,256,320,256,256,256};
  const int CO[8]    = {0,40,40,40,0,40,40,40};
  const int WOFF8[8] = {0,2048,10240,18432,26624,36864,45056,53248};

  for (int l = 0; l < 8; ++l) {
    const int nc = KP[l] >> 5;
    const int co = CO[l];
    const int wbase = WOFF8[l] + ((wv << 2) << 6) + lane;  // + (kc*16)*64 + nt*64 per frag

    f32x4 acc[4][4];
#pragma unroll
    for (int mt = 0; mt < 4; ++mt)
#pragma unroll
      for (int nt = 0; nt < 4; ++nt)
        acc[mt][nt] = (f32x4){0.f, 0.f, 0.f, 0.f};

    for (int kc = 0; kc < nc; ++kc) {
      f16x8 bfr[4];
#pragma unroll
      for (int nt = 0; nt < 4; ++nt)
        bfr[nt] = wf[wbase + (kc << 10) + (nt << 6)];
      f16x8 afr[4];
#pragma unroll
      for (int mt = 0; mt < 4; ++mt)
        afr[mt] = *(const f16x8*)&X[(mt*16 + l16) * S + co + kc*32 + quad*8];
#pragma unroll
      for (int mt = 0; mt < 4; ++mt)
#pragma unroll
        for (int nt = 0; nt < 4; ++nt)
          acc[mt][nt] = __builtin_amdgcn_mfma_f32_16x16x32_f16(afr[mt], bfr[nt], acc[mt][nt], 0, 0, 0);
    }

    float bv[4];
    const float* bp = P.b[l];
#pragma unroll
    for (int nt = 0; nt < 4; ++nt)
      bv[nt] = bp[(wv << 6) + (nt << 4) + l16];

    __syncthreads();   // all reads of X done before in-place overwrite
#pragma unroll
    for (int mt = 0; mt < 4; ++mt)
#pragma unroll
      for (int nt = 0; nt < 4; ++nt)
#pragma unroll
        for (int r = 0; r < 4; ++r) {
          float v = acc[mt][nt][r] + bv[nt];
          v = fmaxf(v, 0.f);
          X[(mt*16 + quad*4 + r) * S + 40 + (wv << 6) + (nt << 4) + l16] = (_Float16)v;
        }
    __syncthreads();
  }

  // ---- SDF head: out = x7 @ wsdf + bsdf; 4 threads per point ----
  {
    const int p = tid >> 2, part = tid & 3;
    float acc = 0.f;
    const _Float16* xr = &X[p * S + 40 + part * 64];
#pragma unroll
    for (int j = 0; j < 8; ++j) {
      f16x8 h = *(const f16x8*)&xr[j * 8];
#pragma unroll
      for (int e = 0; e < 8; ++e)
        acc += (float)h[e] * wsdf[part * 64 + j * 8 + e];
    }
    acc += __shfl_down(acc, 1);
    acc += __shfl_down(acc, 2);
    if (part == 0) out[blk * T + p] = acc + bsdf[0];
  }
}

extern "C" void kernel_launch(void* const* d_in, const int* in_sizes, int n_in,
                              void* d_out, int out_size, void* d_ws, size_t ws_size,
                              hipStream_t stream) {
  const float* points = (const float*)d_in[0];
  LayerPtrs P;
  for (int i = 0; i < 8; ++i) {
    P.w[i] = (const float*)d_in[1 + 2*i];
    P.b[i] = (const float*)d_in[2 + 2*i];
  }
  const float* wsdf = (const float*)d_in[17];
  const float* bsdf = (const float*)d_in[18];
  f16x8* wf = (f16x8*)d_ws;   // needs 983040 B

  int N = in_sizes[0] / 3;
  prep_weights<<<240, 256, 0, stream>>>(P, wf);
  mlp_fused<<<N / T, 256, 0, stream>>>(points, P, wf, wsdf, bsdf, (float*)d_out);
}

// Round 2
// 354.346 us; speedup vs baseline: 1.0142x; 1.0142x over previous
//
#include <hip/hip_runtime.h>
#include <hip/hip_fp16.h>

typedef _Float16 f16x8 __attribute__((ext_vector_type(8)));
typedef _Float16 f16x4 __attribute__((ext_vector_type(4)));
typedef float    f32x16 __attribute__((ext_vector_type(16)));
typedef float    f32x4 __attribute__((ext_vector_type(4)));

#define SH 264   // H row stride (fp16): 256 + 8; multiple of 8 for 16B-aligned b128
#define SE 56    // E row stride (fp16): 48 used + pad; multiple of 8

struct LayerPtrs {
  const float* w[8];
  const float* b[8];
};

// Weight fragments in d_ws, A-operand layout for mfma_f32_32x32x16_f16:
//   A[m=lane&31][k=(lane>>5)*8+j], m = mtile*32 + (lane&31), k = kc*16 + (lane>>5)*8 + j
// index = WOFF[l] + (kc*8 + mtile)*64 + lane, element j.
// A = W^T (hidden x din), so value = W[k][m]. L0: k>=39 -> 0 (pad to 48).
// L4: kc<3 -> emb segment (k<39 real, else 0); kc>=3 -> hidden segment row 39+k'.
__global__ void prep_weights(LayerPtrs P, f16x8* __restrict__ wf) {
  int gid = blockIdx.x * 256 + threadIdx.x;
  if (gid >= 60416) return;
  const int OFF[9] = {0,1536,9728,17920,26112,35840,44032,52224,60416};
  int l = 0;
  while (gid >= OFF[l+1]) ++l;
  int f = gid - OFF[l];
  int lane = f & 63;
  int t = f >> 6;
  int mtile = t & 7;
  int kc = t >> 3;
  int col = mtile * 32 + (lane & 31);      // hidden (m)
  int kb  = (lane >> 5) * 8;
  const float* w = P.w[l];
  f16x8 v;
#pragma unroll
  for (int j = 0; j < 8; ++j) {
    float x = 0.f;
    if (l == 4) {
      if (kc < 3) {
        int k = kc * 16 + kb + j;
        if (k < 39) x = w[k * 256 + col];
      } else {
        int k = (kc - 3) * 16 + kb + j;    // 0..255
        x = w[(39 + k) * 256 + col];
      }
    } else if (l == 0) {
      int k = kc * 16 + kb + j;
      if (k < 39) x = w[k * 256 + col];
    } else {
      int k = kc * 16 + kb + j;
      x = w[k * 256 + col];
    }
    v[j] = (_Float16)x;
  }
  wf[gid] = v;
}

template<int NKC>
__device__ __forceinline__ void mm(const f16x8* __restrict__ wb,
                                   const _Float16* __restrict__ b0,
                                   const _Float16* __restrict__ b1,
                                   f32x16 acc[2][2]) {
#pragma unroll
  for (int kc = 0; kc < NKC; ++kc) {
    f16x8 a0 = wb[(kc * 8 + 0) * 64];
    f16x8 a1 = wb[(kc * 8 + 1) * 64];
    f16x8 v0 = *(const f16x8*)(b0 + kc * 16);
    f16x8 v1 = *(const f16x8*)(b1 + kc * 16);
    acc[0][0] = __builtin_amdgcn_mfma_f32_32x32x16_f16(a0, v0, acc[0][0], 0, 0, 0);
    acc[0][1] = __builtin_amdgcn_mfma_f32_32x32x16_f16(a0, v1, acc[0][1], 0, 0, 0);
    acc[1][0] = __builtin_amdgcn_mfma_f32_32x32x16_f16(a1, v0, acc[1][0], 0, 0, 0);
    acc[1][1] = __builtin_amdgcn_mfma_f32_32x32x16_f16(a1, v1, acc[1][1], 0, 0, 0);
  }
}

__device__ __forceinline__ void zero_acc(f32x16 acc[2][2]) {
#pragma unroll
  for (int mt = 0; mt < 2; ++mt)
#pragma unroll
    for (int nt = 0; nt < 2; ++nt)
#pragma unroll
      for (int r = 0; r < 16; ++r) acc[mt][nt][r] = 0.f;
}

// C/D 32x32: col = lane&31 (point), row = (reg&3) + 8*(reg>>2) + 4*(lane>>5) (hidden)
// -> reg 4g+r maps to hidden = base + mt*32 + 8g + 4h + r: 4 consecutive -> b64 write.
__device__ __forceinline__ void store_act(f32x16 acc[2][2], const float* __restrict__ bp,
                                          int wv, int lane, _Float16* __restrict__ H) {
  int p0 = lane & 31, h = lane >> 5;
#pragma unroll
  for (int mt = 0; mt < 2; ++mt) {
    int hb = wv * 64 + mt * 32 + 4 * h;
#pragma unroll
    for (int g = 0; g < 4; ++g) {
      f32x4 bv = *(const f32x4*)&bp[hb + 8 * g];
#pragma unroll
      for (int nt = 0; nt < 2; ++nt) {
        f16x4 o;
#pragma unroll
        for (int r = 0; r < 4; ++r) {
          float x = acc[mt][nt][4 * g + r] + bv[r];
          o[r] = (_Float16)fmaxf(x, 0.f);
        }
        *(f16x4*)&H[(nt * 32 + p0) * SH + hb + 8 * g] = o;
      }
    }
  }
}

__global__ __launch_bounds__(256, 4)
void mlp_fused(const float* __restrict__ points,
               LayerPtrs P,
               const f16x8* __restrict__ wf,
               const float* __restrict__ wsdf,
               const float* __restrict__ bsdf,
               float* __restrict__ out) {
  __shared__ __align__(16) _Float16 H[64 * SH];   // 33792 B
  __shared__ __align__(16) _Float16 E[64 * SE];   // 7168 B  -> total 40960 = 4 blocks/CU
  const int tid = threadIdx.x;
  const int blk = blockIdx.x;

  // ---- embedding into E: cols 0..38 = [sin(18)|cos(18)|xyz], 39..55 zero ----
  if (tid < 64) {
    int p = blk * 64 + tid;
    float xyz[3] = {points[p * 3 + 0], points[p * 3 + 1], points[p * 3 + 2]};
    _Float16* row = &E[tid * SE];
#pragma unroll
    for (int c = 0; c < 3; ++c) {
      float fr = 1.f;
#pragma unroll
      for (int k = 0; k < 6; ++k) {
        float e = xyz[c] * fr;
        row[c * 6 + k]      = (_Float16)sinf(e);
        row[18 + c * 6 + k] = (_Float16)cosf(e);
        fr *= 2.f;
      }
      row[36 + c] = (_Float16)xyz[c];
    }
    for (int c = 39; c < SE; ++c) row[c] = (_Float16)0.f;
  }
  __syncthreads();

  const int lane = tid & 63;
  const int wv   = tid >> 6;          // wave -> hidden slice [64*wv, 64*wv+64)
  const int p0   = lane & 31;
  const int h    = lane >> 5;

  const _Float16* e0 = &E[p0 * SE + h * 8];
  const _Float16* e1 = &E[(32 + p0) * SE + h * 8];
  const _Float16* h0 = &H[p0 * SH + h * 8];
  const _Float16* h1 = &H[(32 + p0) * SH + h * 8];
  const f16x8* wb = wf + wv * 128 + lane;   // + WOFF[l] + (kc*8+mt)*64 per frag

  const int WOFF[8] = {0,1536,9728,17920,26112,35840,44032,52224};

  f32x16 acc[2][2];

  // L0: read E, write H (disjoint -> single barrier after)
  zero_acc(acc);
  mm<3>(wb + WOFF[0], e0, e1, acc);
  store_act(acc, P.b[0], wv, lane, H);
  __syncthreads();

  // L1..L3: in-place H (barrier between read and write phases)
#pragma unroll
  for (int l = 1; l < 4; ++l) {
    zero_acc(acc);
    mm<16>(wb + WOFF[l], h0, h1, acc);
    __syncthreads();
    store_act(acc, P.b[l], wv, lane, H);
    __syncthreads();
  }

  // L4: concat input = E (3 kc) + H (16 kc)
  zero_acc(acc);
  mm<3>(wb + WOFF[4], e0, e1, acc);
  mm<16>(wb + WOFF[4] + 3 * 512, h0, h1, acc);
  __syncthreads();
  store_act(acc, P.b[4], wv, lane, H);
  __syncthreads();

  // L5..L7
#pragma unroll
  for (int l = 5; l < 8; ++l) {
    zero_acc(acc);
    mm<16>(wb + WOFF[l], h0, h1, acc);
    __syncthreads();
    store_act(acc, P.b[l], wv, lane, H);
    __syncthreads();
  }

  // ---- SDF head: 4 threads per point ----
  {
    const int p = tid >> 2, part = tid & 3;
    float a = 0.f;
    const _Float16* xr = &H[p * SH + part * 64];
#pragma unroll
    for (int j = 0; j < 8; ++j) {
      f16x8 hh = *(const f16x8*)&xr[j * 8];
      f32x4 wa = *(const f32x4*)&wsdf[part * 64 + j * 8];
      f32x4 wc = *(const f32x4*)&wsdf[part * 64 + j * 8 + 4];
      a += (float)hh[0] * wa[0] + (float)hh[1] * wa[1]
         + (float)hh[2] * wa[2] + (float)hh[3] * wa[3]
         + (float)hh[4] * wc[0] + (float)hh[5] * wc[1]
         + (float)hh[6] * wc[2] + (float)hh[7] * wc[3];
    }
    a += __shfl_down(a, 1);
    a += __shfl_down(a, 2);
    if (part == 0) out[blk * 64 + p] = a + bsdf[0];
  }
}

extern "C" void kernel_launch(void* const* d_in, const int* in_sizes, int n_in,
                              void* d_out, int out_size, void* d_ws, size_t ws_size,
                              hipStream_t stream) {
  const float* points = (const float*)d_in[0];
  LayerPtrs P;
  for (int i = 0; i < 8; ++i) {
    P.w[i] = (const float*)d_in[1 + 2 * i];
    P.b[i] = (const float*)d_in[2 + 2 * i];
  }
  const float* wsdf = (const float*)d_in[17];
  const float* bsdf = (const float*)d_in[18];
  f16x8* wf = (f16x8*)d_ws;   // needs 966656 B

  int N = in_sizes[0] / 3;    // 262144
  prep_weights<<<236, 256, 0, stream>>>(P, wf);
  mlp_fused<<<N / 64, 256, 0, stream>>>(points, P, wf, wsdf, bsdf, (float*)d_out);
}

// Round 3
// 317.955 us; speedup vs baseline: 1.1303x; 1.1145x over previous
//
#include <hip/hip_runtime.h>
#include <hip/hip_fp16.h>

typedef _Float16 f16x8 __attribute__((ext_vector_type(8)));
typedef _Float16 f16x4 __attribute__((ext_vector_type(4)));
typedef float    f32x16 __attribute__((ext_vector_type(16)));
typedef float    f32x4 __attribute__((ext_vector_type(4)));

#define SH 264   // H row stride (fp16); mult of 8 (16B-aligned b128), 264/2 % 32 == 4 -> mild alias
#define SE 48    // E row stride (fp16): 48 = padded K of embedding
#define PTS 128  // points per block

struct LayerPtrs {
  const float* w[8];
  const float* b[8];
};

// Weight fragments in d_ws, A-operand layout for mfma_f32_32x32x16_f16:
//   m = mtile*32 + (lane&31), k = kc*16 + (lane>>5)*8 + j ; value = W[k][m]
// index = WOFF[l] + (kc*8 + mtile)*64 + lane, element j. (unchanged from round 2)
__global__ void prep_weights(LayerPtrs P, f16x8* __restrict__ wf) {
  int gid = blockIdx.x * 256 + threadIdx.x;
  if (gid >= 60416) return;
  const int OFF[9] = {0,1536,9728,17920,26112,35840,44032,52224,60416};
  int l = 0;
  while (gid >= OFF[l+1]) ++l;
  int f = gid - OFF[l];
  int lane = f & 63;
  int t = f >> 6;
  int mtile = t & 7;
  int kc = t >> 3;
  int col = mtile * 32 + (lane & 31);
  int kb  = (lane >> 5) * 8;
  const float* w = P.w[l];
  f16x8 v;
#pragma unroll
  for (int j = 0; j < 8; ++j) {
    float x = 0.f;
    if (l == 4) {
      if (kc < 3) {
        int k = kc * 16 + kb + j;
        if (k < 39) x = w[k * 256 + col];
      } else {
        int k = (kc - 3) * 16 + kb + j;
        x = w[(39 + k) * 256 + col];
      }
    } else if (l == 0) {
      int k = kc * 16 + kb + j;
      if (k < 39) x = w[k * 256 + col];
    } else {
      int k = kc * 16 + kb + j;
      x = w[k * 256 + col];
    }
    v[j] = (_Float16)x;
  }
  wf[gid] = v;
}

// 8 independent MFMA chains per kc: 2 m-tiles (weights, global) x 4 n-tiles (points, LDS)
template<int NKC, int STRIDE>
__device__ __forceinline__ void mm(const f16x8* __restrict__ wb,
                                   const _Float16* __restrict__ b0,
                                   const _Float16* __restrict__ b1,
                                   const _Float16* __restrict__ b2,
                                   const _Float16* __restrict__ b3,
                                   f32x16 acc[2][4]) {
#pragma unroll
  for (int kc = 0; kc < NKC; ++kc) {
    f16x8 a0 = wb[(kc * 8 + 0) * 64];
    f16x8 a1 = wb[(kc * 8 + 1) * 64];
    f16x8 v0 = *(const f16x8*)(b0 + kc * 16);
    f16x8 v1 = *(const f16x8*)(b1 + kc * 16);
    f16x8 v2 = *(const f16x8*)(b2 + kc * 16);
    f16x8 v3 = *(const f16x8*)(b3 + kc * 16);
    acc[0][0] = __builtin_amdgcn_mfma_f32_32x32x16_f16(a0, v0, acc[0][0], 0, 0, 0);
    acc[0][1] = __builtin_amdgcn_mfma_f32_32x32x16_f16(a0, v1, acc[0][1], 0, 0, 0);
    acc[0][2] = __builtin_amdgcn_mfma_f32_32x32x16_f16(a0, v2, acc[0][2], 0, 0, 0);
    acc[0][3] = __builtin_amdgcn_mfma_f32_32x32x16_f16(a0, v3, acc[0][3], 0, 0, 0);
    acc[1][0] = __builtin_amdgcn_mfma_f32_32x32x16_f16(a1, v0, acc[1][0], 0, 0, 0);
    acc[1][1] = __builtin_amdgcn_mfma_f32_32x32x16_f16(a1, v1, acc[1][1], 0, 0, 0);
    acc[1][2] = __builtin_amdgcn_mfma_f32_32x32x16_f16(a1, v2, acc[1][2], 0, 0, 0);
    acc[1][3] = __builtin_amdgcn_mfma_f32_32x32x16_f16(a1, v3, acc[1][3], 0, 0, 0);
  }
}

__device__ __forceinline__ void zero_acc(f32x16 acc[2][4]) {
#pragma unroll
  for (int mt = 0; mt < 2; ++mt)
#pragma unroll
    for (int nt = 0; nt < 4; ++nt)
#pragma unroll
      for (int r = 0; r < 16; ++r) acc[mt][nt][r] = 0.f;
}

// C/D 32x32: col(point) = lane&31, row(hidden) = (reg&3) + 8*(reg>>2) + 4*(lane>>5)
__device__ __forceinline__ void store_act(f32x16 acc[2][4], const float* __restrict__ bp,
                                          int wv, int lane, _Float16* __restrict__ H) {
  int p0 = lane & 31, h = lane >> 5;
#pragma unroll
  for (int mt = 0; mt < 2; ++mt) {
    int hb = wv * 64 + mt * 32 + 4 * h;
#pragma unroll
    for (int g = 0; g < 4; ++g) {
      f32x4 bv = *(const f32x4*)&bp[hb + 8 * g];
#pragma unroll
      for (int nt = 0; nt < 4; ++nt) {
        f16x4 o;
#pragma unroll
        for (int r = 0; r < 4; ++r) {
          float x = acc[mt][nt][4 * g + r] + bv[r];
          o[r] = (_Float16)fmaxf(x, 0.f);
        }
        *(f16x4*)&H[(nt * 32 + p0) * SH + hb + 8 * g] = o;
      }
    }
  }
}

__global__ __launch_bounds__(256, 2)
void mlp_fused(const float* __restrict__ points,
               LayerPtrs P,
               const f16x8* __restrict__ wf,
               const float* __restrict__ wsdf,
               const float* __restrict__ bsdf,
               float* __restrict__ out) {
  __shared__ __align__(16) _Float16 H[PTS * SH];   // 67584 B
  __shared__ __align__(16) _Float16 E[PTS * SE];   // 12288 B -> 79872 total, 2 blocks/CU
  const int tid = threadIdx.x;
  const int blk = blockIdx.x;

  // ---- embedding into E: cols 0..38 = [sin(18)|cos(18)|xyz], 39..47 zero ----
  if (tid < PTS) {
    int p = blk * PTS + tid;
    float xyz[3] = {points[p * 3 + 0], points[p * 3 + 1], points[p * 3 + 2]};
    _Float16* row = &E[tid * SE];
#pragma unroll
    for (int c = 0; c < 3; ++c) {
      float fr = 1.f;
#pragma unroll
      for (int k = 0; k < 6; ++k) {
        float e = xyz[c] * fr;
        row[c * 6 + k]      = (_Float16)sinf(e);
        row[18 + c * 6 + k] = (_Float16)cosf(e);
        fr *= 2.f;
      }
      row[36 + c] = (_Float16)xyz[c];
    }
#pragma unroll
    for (int c = 39; c < SE; ++c) row[c] = (_Float16)0.f;
  }
  __syncthreads();

  const int lane = tid & 63;
  const int wv   = tid >> 6;          // wave -> hidden slice [64*wv, 64*wv+64)
  const int p0   = lane & 31;
  const int h    = lane >> 5;

  const _Float16* e0 = &E[p0 * SE + h * 8];
  const _Float16* e1 = &E[(32 + p0) * SE + h * 8];
  const _Float16* e2 = &E[(64 + p0) * SE + h * 8];
  const _Float16* e3 = &E[(96 + p0) * SE + h * 8];
  const _Float16* h0 = &H[p0 * SH + h * 8];
  const _Float16* h1 = &H[(32 + p0) * SH + h * 8];
  const _Float16* h2 = &H[(64 + p0) * SH + h * 8];
  const _Float16* h3 = &H[(96 + p0) * SH + h * 8];
  const f16x8* wb = wf + wv * 128 + lane;

  const int WOFF[8] = {0,1536,9728,17920,26112,35840,44032,52224};

  f32x16 acc[2][4];

  // L0: read E, write H (disjoint)
  zero_acc(acc);
  mm<3, SE>(wb + WOFF[0], e0, e1, e2, e3, acc);
  store_act(acc, P.b[0], wv, lane, H);
  __syncthreads();

  // L1..L3: in-place H
#pragma unroll
  for (int l = 1; l < 4; ++l) {
    zero_acc(acc);
    mm<16, SH>(wb + WOFF[l], h0, h1, h2, h3, acc);
    __syncthreads();
    store_act(acc, P.b[l], wv, lane, H);
    __syncthreads();
  }

  // L4: concat input = E (3 kc) + H (16 kc)
  zero_acc(acc);
  mm<3, SE>(wb + WOFF[4], e0, e1, e2, e3, acc);
  mm<16, SH>(wb + WOFF[4] + 3 * 512, h0, h1, h2, h3, acc);
  __syncthreads();
  store_act(acc, P.b[4], wv, lane, H);
  __syncthreads();

  // L5..L7
#pragma unroll
  for (int l = 5; l < 8; ++l) {
    zero_acc(acc);
    mm<16, SH>(wb + WOFF[l], h0, h1, h2, h3, acc);
    __syncthreads();
    store_act(acc, P.b[l], wv, lane, H);
    __syncthreads();
  }

  // ---- SDF head: 2 threads per point ----
  {
    const int p = tid >> 1, part = tid & 1;
    float a = 0.f;
    const _Float16* xr = &H[p * SH + part * 128];
#pragma unroll
    for (int j = 0; j < 16; ++j) {
      f16x8 hh = *(const f16x8*)&xr[j * 8];
      f32x4 wa = *(const f32x4*)&wsdf[part * 128 + j * 8];
      f32x4 wc = *(const f32x4*)&wsdf[part * 128 + j * 8 + 4];
      a += (float)hh[0] * wa[0] + (float)hh[1] * wa[1]
         + (float)hh[2] * wa[2] + (float)hh[3] * wa[3]
         + (float)hh[4] * wc[0] + (float)hh[5] * wc[1]
         + (float)hh[6] * wc[2] + (float)hh[7] * wc[3];
    }
    a += __shfl_down(a, 1);
    if (part == 0) out[blk * PTS + p] = a + bsdf[0];
  }
}

extern "C" void kernel_launch(void* const* d_in, const int* in_sizes, int n_in,
                              void* d_out, int out_size, void* d_ws, size_t ws_size,
                              hipStream_t stream) {
  const float* points = (const float*)d_in[0];
  LayerPtrs P;
  for (int i = 0; i < 8; ++i) {
    P.w[i] = (const float*)d_in[1 + 2 * i];
    P.b[i] = (const float*)d_in[2 + 2 * i];
  }
  const float* wsdf = (const float*)d_in[17];
  const float* bsdf = (const float*)d_in[18];
  f16x8* wf = (f16x8*)d_ws;   // needs 966656 B

  int N = in_sizes[0] / 3;    // 262144
  prep_weights<<<236, 256, 0, stream>>>(P, wf);
  mlp_fused<<<N / PTS, 256, 0, stream>>>(points, P, wf, wsdf, bsdf, (float*)d_out);
}